// Round 3
// baseline (393.251 us; speedup 1.0000x reference)
//
#include <hip/hip_runtime.h>

// layer_3d_dep_53300544143949 — MI355X (gfx950)
// B=64, C=8, O=8, M=32, K=32, NR=8, NT=8. ALL inputs and output are FLOAT32
// (reference is jnp.float32; R1's zero-output signature proved the bf16-input
// assumption wrong: f32 gamma read as bf16 gave g=0 and zeroed d_out).
// K0 zero-stats | K1 meanM f32 (ws) | K2 main (pre-BN -> d_out, stats atomics) | K3 BN in-place.
// ws use: 256 B stats + 16 MB... no: meanM = 512*2048 f32 = 4 MB. Total ~4.2 MB.

using u32 = unsigned int;

__device__ __forceinline__ void ld8f(const float* p, float* f) {
  float4 a = *(const float4*)p;
  float4 b = *(const float4*)(p + 4);
  f[0] = a.x; f[1] = a.y; f[2] = a.z; f[3] = a.w;
  f[4] = b.x; f[5] = b.y; f[6] = b.z; f[7] = b.w;
}
__device__ __forceinline__ void st8f(float* p, const float* f) {
  *(float4*)p = make_float4(f[0], f[1], f[2], f[3]);
  *(float4*)(p + 4) = make_float4(f[4], f[5], f[6], f[7]);
}
__device__ __forceinline__ float fast_tanh(float x) {
  // tanh(x) = 1 - 2/(e^{2x}+1)
  float e = __expf(2.0f * x);
  return 1.0f - 2.0f / (e + 1.0f);
}

// ---------------- K0: zero the stats region ----------------
__global__ void k0_zero(float* __restrict__ stats) {
  if (threadIdx.x < 16) stats[threadIdx.x] = 0.0f;
}

// ---------------- K1: meanM = mean_m(A)  (f32) ----------------
// grid 512 = b*8+c; 256 thr; thread covers krt slice tid*8..tid*8+7.
__global__ void k1_meanm(const float* __restrict__ A, float* __restrict__ meanM) {
  const int bc = blockIdx.x;
  const int tid = threadIdx.x;
  const float* base = A + (size_t)bc * 65536 + tid * 8;
  float acc8[8];
#pragma unroll
  for (int t = 0; t < 8; ++t) acc8[t] = 0.0f;
  for (int m = 0; m < 32; ++m) {
    float f[8];
    ld8f(base + m * 2048, f);
#pragma unroll
    for (int t = 0; t < 8; ++t) acc8[t] += f[t];
  }
#pragma unroll
  for (int t = 0; t < 8; ++t) acc8[t] *= (1.0f / 32.0f);
  st8f(meanM + bc * 2048 + tid * 8, acc8);
}

// ---------------- K2: main ----------------
// grid 2048 = (b<<5)|m; 256 thr. (k,r)-view: k=tid>>3, r=tid&7 (r = lane bits 0..2).
__global__ __launch_bounds__(256, 2) void k2_main(
    const float* __restrict__ A,
    const float* __restrict__ meanM,
    const float* __restrict__ P1,
    const float* __restrict__ P2,
    const float* __restrict__ P3,
    const float* __restrict__ P4,
    const float* __restrict__ P5,
    const float* __restrict__ Wq,
    const float* __restrict__ Wk,
    float* __restrict__ outp,
    float* __restrict__ stats) {
  __shared__ float qb[8 * 260];
  __shared__ float kb[8 * 260];
  __shared__ float vb[8 * 260];
  __shared__ float a5b[8 * 260];
  __shared__ float sred[64];

  const int tid = threadIdx.x;
  const int b = blockIdx.x >> 5;
  const int m = blockIdx.x & 31;
  const int k = tid >> 3;
  const int r = tid & 7;

  float acc[8][8];
  float tr[8][8];
#pragma unroll
  for (int o = 0; o < 8; ++o)
#pragma unroll
    for (int t = 0; t < 8; ++t) acc[o][t] = 0.0f;

  // Per-c: load A row, build tr (mean over r via lane-xor shuffles), fold A1/A3/A4.
#pragma unroll
  for (int c = 0; c < 8; ++c) {
    float ar[8];
    ld8f(A + ((size_t)((b * 8 + c) * 32 + m) * 2048 + tid * 8), ar);
#pragma unroll
    for (int t = 0; t < 8; ++t) {
      float x = ar[t];
      x += __shfl_xor(x, 1, 64);
      x += __shfl_xor(x, 2, 64);
      x += __shfl_xor(x, 4, 64);
      tr[c][t] = x * 0.125f;
    }
    const float mtc = (ar[0] + ar[1] + ar[2] + ar[3] +
                       ar[4] + ar[5] + ar[6] + ar[7]) * 0.125f;
#pragma unroll
    for (int o = 0; o < 8; ++o) {
      const float w1 = P1[o * 8 + c];
      const float w4 = 0.5f * P4[o * 8 + c];
      const float w3 = 0.1f * P3[o * 8 + c];
#pragma unroll
      for (int t = 0; t < 8; ++t)
        acc[o][t] = fmaf(w1, ar[t], fmaf(w4, tr[c][t], fmaf(w3, mtc, acc[o][t])));
    }
  }

  // A2 fold: 0.1 * P2 (x) meanM (broadcast over m)
#pragma unroll
  for (int c = 0; c < 8; ++c) {
    float m8[8];
    ld8f(meanM + ((b * 8 + c) * 2048 + tid * 8), m8);
#pragma unroll
    for (int o = 0; o < 8; ++o) {
      const float w2 = 0.1f * P2[o * 8 + c];
#pragma unroll
      for (int t = 0; t < 8; ++t) acc[o][t] = fmaf(w2, m8[t], acc[o][t]);
    }
  }

  // qkv for o = r (each (o,k) row written exactly once)
  {
    float qv[8], kv[8], vv[8];
#pragma unroll
    for (int t = 0; t < 8; ++t) { qv[t] = 0.0f; kv[t] = 0.0f; vv[t] = 0.0f; }
#pragma unroll
    for (int c = 0; c < 8; ++c) {
      const float wq = Wq[r * 8 + c];
      const float wk = Wk[r * 8 + c];
      const float wv = P5[r * 8 + c];
#pragma unroll
      for (int t = 0; t < 8; ++t) {
        qv[t] = fmaf(wq, tr[c][t], qv[t]);
        kv[t] = fmaf(wk, tr[c][t], kv[t]);
        vv[t] = fmaf(wv, tr[c][t], vv[t]);
      }
    }
    st8f(&qb[r * 260 + k * 8], qv);
    st8f(&kb[r * 260 + k * 8], kv);
    st8f(&vb[r * 260 + k * 8], vv);
  }
  __syncthreads();

  // Attention: thread = (o, kq, lo): 4 k-rows x 8 l-rows register tile
  {
    const int o = tid >> 5;
    const int kq = (tid >> 2) & 7;
    const int lo = tid & 3;
    float qf[4][8];
#pragma unroll
    for (int kl = 0; kl < 4; ++kl)
      ld8f(&qb[o * 260 + (kq * 4 + kl) * 8], qf[kl]);
    float a5p[4][8];
#pragma unroll
    for (int kl = 0; kl < 4; ++kl)
#pragma unroll
      for (int t = 0; t < 8; ++t) a5p[kl][t] = 0.0f;

#pragma unroll
    for (int ll = 0; ll < 8; ++ll) {
      const int l = lo * 8 + ll;
      float krw[8];
      ld8f(&kb[o * 260 + l * 8], krw);
      float al[4];
#pragma unroll
      for (int kl = 0; kl < 4; ++kl) {
        float s = 0.0f;
#pragma unroll
        for (int t = 0; t < 8; ++t) s = fmaf(qf[kl][t], krw[t], s);
        al[kl] = fast_tanh(s * 0.125f);  // /NT
      }
      float vrw[8];
      ld8f(&vb[o * 260 + l * 8], vrw);
#pragma unroll
      for (int kl = 0; kl < 4; ++kl)
#pragma unroll
        for (int t = 0; t < 8; ++t)
          a5p[kl][t] = fmaf(al[kl], vrw[t], a5p[kl][t]);
    }
    // reduce over the 4 l-octs (lane bits 0..1), scale by 2/Kd = 0.0625
#pragma unroll
    for (int kl = 0; kl < 4; ++kl)
#pragma unroll
      for (int t = 0; t < 8; ++t) {
        float x = a5p[kl][t];
        x += __shfl_xor(x, 1, 64);
        x += __shfl_xor(x, 2, 64);
        a5p[kl][t] = x * 0.0625f;
      }
#pragma unroll
    for (int kl = 0; kl < 4; ++kl) {
      const float w0 = lo == 0 ? a5p[kl][0] : lo == 1 ? a5p[kl][2]
                      : lo == 2 ? a5p[kl][4] : a5p[kl][6];
      const float w1 = lo == 0 ? a5p[kl][1] : lo == 1 ? a5p[kl][3]
                      : lo == 2 ? a5p[kl][5] : a5p[kl][7];
      *(float2*)&a5b[o * 260 + (kq * 4 + kl) * 8 + lo * 2] = make_float2(w0, w1);
    }
  }
  __syncthreads();

  // Epilogue: +A5, ReLU, stats, f32 store (pre-BN) into d_out
  float psum[8], psq[8];
#pragma unroll
  for (int o = 0; o < 8; ++o) { psum[o] = 0.0f; psq[o] = 0.0f; }
  const size_t outbase = (size_t)(b * 256 + m) * 2048 + tid * 8;
#pragma unroll
  for (int o = 0; o < 8; ++o) {
    float a5f[8];
    ld8f(&a5b[o * 260 + k * 8], a5f);
    float x8[8];
#pragma unroll
    for (int t = 0; t < 8; ++t) {
      float x = acc[o][t] + a5f[t];
      x = fmaxf(x, 0.0f);
      psum[o] += x;
      psq[o] = fmaf(x, x, psq[o]);
      x8[t] = x;
    }
    st8f(outp + (outbase + o * 65536), x8);
  }
  // stats: wave butterfly -> LDS -> 16 global atomics
#pragma unroll
  for (int o = 0; o < 8; ++o) {
    float s = psum[o], q = psq[o];
#pragma unroll
    for (int mask = 32; mask >= 1; mask >>= 1) {
      s += __shfl_xor(s, mask, 64);
      q += __shfl_xor(q, mask, 64);
    }
    psum[o] = s; psq[o] = q;
  }
  const int lane = tid & 63;
  const int wid = tid >> 6;
  if (lane == 0) {
#pragma unroll
    for (int o = 0; o < 8; ++o) {
      sred[wid * 16 + o * 2] = psum[o];
      sred[wid * 16 + o * 2 + 1] = psq[o];
    }
  }
  __syncthreads();
  if (tid < 16) {
    float s = sred[tid] + sred[16 + tid] + sred[32 + tid] + sred[48 + tid];
    atomicAdd(&stats[tid], s);
  }
}

// ---------------- K3: BN normalize in place ----------------
__global__ void k3_norm(float* __restrict__ outp,
                        const float* __restrict__ stats,
                        const float* __restrict__ gamma,
                        const float* __restrict__ beta) {
  const int idx = blockIdx.x * 256 + threadIdx.x;
  const size_t e0 = (size_t)idx * 8;
  const int o = (int)(e0 >> 16) & 7;
  const float N = 4194304.0f;  // B*M*K*NR*NT
  const float mean = stats[o * 2] / N;
  float var = stats[o * 2 + 1] / N - mean * mean;
  var = fmaxf(var, 0.0f);
  const float inv = rsqrtf(var + 1e-5f);
  const float g = gamma[o] * inv;
  const float sh = beta[o] - mean * g;
  float f[8];
  ld8f(outp + e0, f);
#pragma unroll
  for (int t = 0; t < 8; ++t) f[t] = fmaf(f[t], g, sh);
  st8f(outp + e0, f);
}

extern "C" void kernel_launch(void* const* d_in, const int* in_sizes, int n_in,
                              void* d_out, int out_size, void* d_ws, size_t ws_size,
                              hipStream_t stream) {
  const float* A  = (const float*)d_in[0];
  const float* P1 = (const float*)d_in[1];
  const float* P2 = (const float*)d_in[2];
  const float* P3 = (const float*)d_in[3];
  const float* P4 = (const float*)d_in[4];
  const float* P5 = (const float*)d_in[5];
  const float* Wq = (const float*)d_in[6];
  const float* Wk = (const float*)d_in[7];
  const float* gamma = (const float*)d_in[8];
  const float* beta  = (const float*)d_in[9];
  float* outp = (float*)d_out;

  // ws layout: [0,64)B stats (16 f32), [256, 256+4MB) meanM f32. Total ~4.2 MB.
  float* stats = (float*)d_ws;
  float* meanM = (float*)((char*)d_ws + 256);

  hipLaunchKernelGGL(k0_zero, dim3(1), dim3(64), 0, stream, stats);
  hipLaunchKernelGGL(k1_meanm, dim3(512), dim3(256), 0, stream, A, meanM);
  hipLaunchKernelGGL(k2_main, dim3(2048), dim3(256), 0, stream,
                     A, meanM, P1, P2, P3, P4, P5, Wq, Wk, outp, stats);
  hipLaunchKernelGGL(k3_norm, dim3(16384), dim3(256), 0, stream,
                     outp, stats, gamma, beta);
}